// Round 7
// baseline (2864.120 us; speedup 1.0000x reference)
//
#include <hip/hip_runtime.h>

#define CD 128   // channels
#define KK 9     // 3x3 kernel taps

typedef __bf16 bf16x8 __attribute__((ext_vector_type(8)));
typedef float  f32x4  __attribute__((ext_vector_type(4)));
typedef float  f32x16 __attribute__((ext_vector_type(16)));

typedef __attribute__((address_space(1))) const void* gas_ptr;
typedef __attribute__((address_space(3))) void*       las_ptr;

// ---------------------------------------------------------------------------
// Transpose + cast W[k][c][o] (f32) -> W_T[k][o][c] (bf16 bits), linear layout.
// ---------------------------------------------------------------------------
__global__ __launch_bounds__(256) void transpose_w(const float* __restrict__ W1,
                                                   const float* __restrict__ W2,
                                                   unsigned short* __restrict__ W1T,
                                                   unsigned short* __restrict__ W2T) {
    __shared__ unsigned short tile[128 * 129];
    const int b = blockIdx.x;            // 0..17
    const int k = (b < KK) ? b : b - KK;
    const float* src = ((b < KK) ? W1 : W2) + k * (CD * CD);
    unsigned short* dst = ((b < KK) ? W1T : W2T) + k * (CD * CD);
    #pragma unroll 4
    for (int p = 0; p < 64; ++p) {
        int idx = p * 256 + threadIdx.x;     // coalesced read W[k][c][o]
        int c = idx >> 7, o = idx & 127;
        __bf16 h = (__bf16)src[idx];
        tile[o * 129 + c] = __builtin_bit_cast(unsigned short, h);
    }
    __syncthreads();
    #pragma unroll 4
    for (int p = 0; p < 64; ++p) {
        int idx = p * 256 + threadIdx.x;     // coalesced write W_T[k][o][c]
        int o = idx >> 7, c = idx & 127;
        dst[idx] = tile[o * 129 + c];
    }
}

// ---------------------------------------------------------------------------
// conv1 — unchanged round-2 structure: wave = 64 sites x 128 out, 256-thr
// block, 2 waves/SIMD, double-buffered 2x32KB weight LDS, cached gathers
// (feats has ~2.6x reuse in L1/L2), cached stores.
// ---------------------------------------------------------------------------
__global__ __launch_bounds__(256, 2) void conv1_kernel(
    const float* __restrict__ feats,
    const unsigned short* __restrict__ WT,  // bf16 W_T[k][o][c] linear
    const int* __restrict__ nbr,
    unsigned short* __restrict__ hout,
    const int n)
{
    __shared__ __align__(16) char wbuf[2][32768];

    const int tid  = threadIdx.x;
    const int lane = tid & 63;
    const int l31  = lane & 31;
    const int kh   = lane >> 5;
    const int wave = tid >> 6;
    const int base = blockIdx.x * 256 + wave * 64;
    const int s0 = base + l31;
    const int s1 = base + 32 + l31;
    const int sc0 = (s0 < n) ? s0 : (n - 1);
    const int sc1 = (s1 < n) ? s1 : (n - 1);

    auto stage = [&](int b, int k) {
        const char* tap = (const char*)(WT + (size_t)k * CD * CD);
        char* lb = &wbuf[b][0];
        #pragma unroll
        for (int i = 0; i < 8; ++i) {
            const int chunk = (i * 4 + wave) * 1024;
            const int d = chunk + lane * 16;
            const int s = d ^ (((d >> 8) & 7) << 4);
            __builtin_amdgcn_global_load_lds((gas_ptr)(tap + s),
                                             (las_ptr)(lb + chunk), 16, 0, 0);
        }
    };

    f32x16 acc[2][4];
    #pragma unroll
    for (int m = 0; m < 2; ++m)
        #pragma unroll
        for (int nf = 0; nf < 4; ++nf)
            #pragma unroll
            for (int i = 0; i < 16; ++i) acc[m][nf][i] = 0.f;

    bf16x8 zed;
    #pragma unroll
    for (int e = 0; e < 8; ++e) zed[e] = (__bf16)0.f;

    int c0 = nbr[(size_t)sc0 * KK];
    int c1 = nbr[(size_t)sc1 * KK];
    stage(0, 0);
    __syncthreads();

    const int swq = (l31 & 7) << 4;

    #pragma unroll 1
    for (int k = 0; k < KK; ++k) {
        int n0 = 0, n1 = 0;
        if (k + 1 < KK) {
            n0 = nbr[(size_t)sc0 * KK + k + 1];
            n1 = nbr[(size_t)sc1 * KK + k + 1];
            stage((k + 1) & 1, k + 1);
        }

        const bool v0 = (unsigned)c0 < (unsigned)n;
        const bool v1 = (unsigned)c1 < (unsigned)n;
        const size_t rr0 = (size_t)(v0 ? c0 : 0) * CD;
        const size_t rr1 = (size_t)(v1 ? c1 : 0) * CD;

        bf16x8 a0[8], a1[8];
        #pragma unroll
        for (int cs = 0; cs < 8; ++cs) {
            const int coff = cs * 16 + kh * 8;
            f32x4 lo0 = *(const f32x4*)(feats + rr0 + coff);
            f32x4 hi0 = *(const f32x4*)(feats + rr0 + coff + 4);
            f32x4 lo1 = *(const f32x4*)(feats + rr1 + coff);
            f32x4 hi1 = *(const f32x4*)(feats + rr1 + coff + 4);
            #pragma unroll
            for (int e = 0; e < 4; ++e) {
                a0[cs][e] = (__bf16)lo0[e]; a0[cs][e + 4] = (__bf16)hi0[e];
                a1[cs][e] = (__bf16)lo1[e]; a1[cs][e + 4] = (__bf16)hi1[e];
            }
            a0[cs] = v0 ? a0[cs] : zed;
            a1[cs] = v1 ? a1[cs] : zed;
        }

        const char* wb = &wbuf[k & 1][0];
        #pragma unroll
        for (int cs = 0; cs < 8; ++cs) {
            #pragma unroll
            for (int nf = 0; nf < 4; ++nf) {
                const int x = ((nf * 32 + l31) << 8) + (cs << 5) + (kh << 4);
                bf16x8 b = *(const bf16x8*)(wb + (x ^ swq));
                acc[0][nf] = __builtin_amdgcn_mfma_f32_32x32x16_bf16(a0[cs], b, acc[0][nf], 0, 0, 0);
                acc[1][nf] = __builtin_amdgcn_mfma_f32_32x32x16_bf16(a1[cs], b, acc[1][nf], 0, 0, 0);
            }
        }

        __syncthreads();
        c0 = n0; c1 = n1;
    }

    #pragma unroll
    for (int m = 0; m < 2; ++m) {
        #pragma unroll
        for (int rg = 0; rg < 16; ++rg) {
            const int row  = (rg & 3) + 8 * (rg >> 2) + 4 * kh;
            const int srow = base + m * 32 + row;
            if (srow < n) {
                #pragma unroll
                for (int nf = 0; nf < 4; ++nf) {
                    float v = acc[m][nf][rg];
                    v = v > 0.f ? v : 0.f;
                    hout[(size_t)srow * CD + nf * 32 + l31] =
                        __builtin_bit_cast(unsigned short, (__bf16)v);
                }
            }
        }
    }
}

// ---------------------------------------------------------------------------
// conv2 — occupancy-maximized: wave = 32 sites x 128 out (acc 64), 512-thr
// block (8 waves), SINGLE 32KB weight buffer -> 4 blocks/CU -> 32 waves/CU
// (8/SIMD, the hardware cap; R3 proved occupancy is conv2's lever:
// 228us @2w -> 152us @4w). Software pipeline: all 9 nbr idx up front,
// tap-(k+1) A-gathers issued before tap-k MFMAs, stage(k+1) in the
// inter-tap barrier gap (drain covered by the 3 other resident blocks).
// NT A-gathers (51MB random stream), NT residual + NT out store.
// ---------------------------------------------------------------------------
__global__ __launch_bounds__(512, 8) void conv2_kernel(
    const float* __restrict__ feats,        // residual
    const unsigned short* __restrict__ asrc,// bf16 hid
    const unsigned short* __restrict__ WT,  // bf16 W_T[k][o][c] linear
    const int* __restrict__ nbr,
    float* __restrict__ fout,
    const int n)
{
    __shared__ __align__(16) char wbuf[32768];

    const int tid  = threadIdx.x;
    const int lane = tid & 63;
    const int l31  = lane & 31;
    const int kh   = lane >> 5;
    const int wave = tid >> 6;              // 0..7
    const int base = blockIdx.x * 256 + wave * 32;
    const int s0 = base + l31;
    const int sc0 = (s0 < n) ? s0 : (n - 1);

    auto stage = [&](int k) {
        const char* tap = (const char*)(WT + (size_t)k * CD * CD);
        #pragma unroll
        for (int i = 0; i < 4; ++i) {
            const int chunk = (i * 8 + wave) * 1024;
            const int d = chunk + lane * 16;
            const int s = d ^ (((d >> 8) & 7) << 4);
            __builtin_amdgcn_global_load_lds((gas_ptr)(tap + s),
                                             (las_ptr)(&wbuf[chunk]), 16, 0, 0);
        }
    };

    // all 9 neighbor indices up front
    int idx[KK];
    #pragma unroll
    for (int k = 0; k < KK; ++k) idx[k] = nbr[(size_t)sc0 * KK + k];

    f32x16 acc[4];
    #pragma unroll
    for (int nf = 0; nf < 4; ++nf)
        #pragma unroll
        for (int i = 0; i < 16; ++i) acc[nf][i] = 0.f;

    bf16x8 zed;
    #pragma unroll
    for (int e = 0; e < 8; ++e) zed[e] = (__bf16)0.f;

    auto gather = [&](int c, bf16x8 (&a)[8]) {
        const bool v = (unsigned)c < (unsigned)n;
        const size_t rr = (size_t)(v ? c : 0) * CD;
        #pragma unroll
        for (int cs = 0; cs < 8; ++cs) {
            const int coff = cs * 16 + kh * 8;
            a[cs] = __builtin_nontemporal_load((const bf16x8*)(asrc + rr + coff));
            a[cs] = v ? a[cs] : zed;
        }
    };

    // prologue: stage tap 0, gather tap 0
    stage(0);
    bf16x8 acur[8], anxt[8];
    gather(idx[0], acur);
    __syncthreads();

    const int swq = (l31 & 7) << 4;

    #pragma unroll 1
    for (int k = 0; k < KK; ++k) {
        if (k + 1 < KK) gather(idx[k + 1], anxt);   // overlaps MFMAs below

        #pragma unroll
        for (int cs = 0; cs < 8; ++cs) {
            #pragma unroll
            for (int nf = 0; nf < 4; ++nf) {
                const int x = ((nf * 32 + l31) << 8) + (cs << 5) + (kh << 4);
                bf16x8 b = *(const bf16x8*)(wbuf + (x ^ swq));
                acc[nf] = __builtin_amdgcn_mfma_f32_32x32x16_bf16(acur[cs], b, acc[nf], 0, 0, 0);
            }
        }

        if (k + 1 < KK) {
            __syncthreads();          // all waves done reading tap k panel
            stage(k + 1);             // restage same buffer
            __syncthreads();          // panel k+1 resident (vmcnt drain)
            #pragma unroll
            for (int cs = 0; cs < 8; ++cs) acur[cs] = anxt[cs];
        }
    }

    // Epilogue: col=lane&31, row=(rg&3)+8*(rg>>2)+4*kh; NT residual + store
    #pragma unroll
    for (int rg = 0; rg < 16; ++rg) {
        const int row  = (rg & 3) + 8 * (rg >> 2) + 4 * kh;
        const int srow = base + row;
        if (srow < n) {
            #pragma unroll
            for (int nf = 0; nf < 4; ++nf) {
                float v = acc[nf][rg];
                const size_t oi = (size_t)srow * CD + nf * 32 + l31;
                v += __builtin_nontemporal_load(feats + oi);
                v = v > 0.f ? v : 0.f;
                __builtin_nontemporal_store(v, fout + oi);
            }
        }
    }
}

extern "C" void kernel_launch(void* const* d_in, const int* in_sizes, int n_in,
                              void* d_out, int out_size, void* d_ws, size_t ws_size,
                              hipStream_t stream) {
    const float* feats = (const float*)d_in[0];
    const int*   nbr   = (const int*)d_in[1];
    const float* W1    = (const float*)d_in[2];
    const float* W2    = (const float*)d_in[3];
    float* out = (float*)d_out;

    const int n = in_sizes[0] / CD;   // active sites (200000)

    unsigned short* hid = (unsigned short*)d_ws;
    unsigned short* W1T = hid + (size_t)n * CD;
    unsigned short* W2T = W1T + KK * CD * CD;

    transpose_w<<<2 * KK, 256, 0, stream>>>(W1, W2, W1T, W2T);

    const int grid = (n + 255) / 256;   // 256 sites per block (both convs)
    conv1_kernel<<<grid, 256, 0, stream>>>(feats, W1T, nbr, hid, n);
    conv2_kernel<<<grid, 512, 0, stream>>>(feats, hid, W2T, nbr, out, n);
}

// Round 8
// 369.487 us; speedup vs baseline: 7.7516x; 7.7516x over previous
//
#include <hip/hip_runtime.h>

#define CD 128   // channels
#define KK 9     // 3x3 kernel taps

typedef __bf16 bf16x8 __attribute__((ext_vector_type(8)));
typedef float  f32x4  __attribute__((ext_vector_type(4)));
typedef float  f32x16 __attribute__((ext_vector_type(16)));

typedef __attribute__((address_space(1))) const void* gas_ptr;
typedef __attribute__((address_space(3))) void*       las_ptr;

// ---------------------------------------------------------------------------
// Transpose + cast W[k][c][o] (f32) -> W_T[k][o][c] (bf16 bits), linear layout.
// ---------------------------------------------------------------------------
__global__ __launch_bounds__(256) void transpose_w(const float* __restrict__ W1,
                                                   const float* __restrict__ W2,
                                                   unsigned short* __restrict__ W1T,
                                                   unsigned short* __restrict__ W2T) {
    __shared__ unsigned short tile[128 * 129];
    const int b = blockIdx.x;            // 0..17
    const int k = (b < KK) ? b : b - KK;
    const float* src = ((b < KK) ? W1 : W2) + k * (CD * CD);
    unsigned short* dst = ((b < KK) ? W1T : W2T) + k * (CD * CD);
    #pragma unroll 4
    for (int p = 0; p < 64; ++p) {
        int idx = p * 256 + threadIdx.x;     // coalesced read W[k][c][o]
        int c = idx >> 7, o = idx & 127;
        __bf16 h = (__bf16)src[idx];
        tile[o * 129 + c] = __builtin_bit_cast(unsigned short, h);
    }
    __syncthreads();
    #pragma unroll 4
    for (int p = 0; p < 64; ++p) {
        int idx = p * 256 + threadIdx.x;     // coalesced write W_T[k][o][c]
        int o = idx >> 7, c = idx & 127;
        dst[idx] = tile[o * 129 + c];
    }
}

// ---------------------------------------------------------------------------
// conv1 — unchanged round-2 structure: wave = 64 sites x 128 out, 256-thr
// block, 2 waves/SIMD, double-buffered 2x32KB weight LDS, cached gathers
// (feats has ~2.6x reuse in L1/L2), cached stores. Measured 65-107 us.
// ---------------------------------------------------------------------------
__global__ __launch_bounds__(256, 2) void conv1_kernel(
    const float* __restrict__ feats,
    const unsigned short* __restrict__ WT,  // bf16 W_T[k][o][c] linear
    const int* __restrict__ nbr,
    unsigned short* __restrict__ hout,
    const int n)
{
    __shared__ __align__(16) char wbuf[2][32768];

    const int tid  = threadIdx.x;
    const int lane = tid & 63;
    const int l31  = lane & 31;
    const int kh   = lane >> 5;
    const int wave = tid >> 6;
    const int base = blockIdx.x * 256 + wave * 64;
    const int s0 = base + l31;
    const int s1 = base + 32 + l31;
    const int sc0 = (s0 < n) ? s0 : (n - 1);
    const int sc1 = (s1 < n) ? s1 : (n - 1);

    auto stage = [&](int b, int k) {
        const char* tap = (const char*)(WT + (size_t)k * CD * CD);
        char* lb = &wbuf[b][0];
        #pragma unroll
        for (int i = 0; i < 8; ++i) {
            const int chunk = (i * 4 + wave) * 1024;
            const int d = chunk + lane * 16;
            const int s = d ^ (((d >> 8) & 7) << 4);
            __builtin_amdgcn_global_load_lds((gas_ptr)(tap + s),
                                             (las_ptr)(lb + chunk), 16, 0, 0);
        }
    };

    f32x16 acc[2][4];
    #pragma unroll
    for (int m = 0; m < 2; ++m)
        #pragma unroll
        for (int nf = 0; nf < 4; ++nf)
            #pragma unroll
            for (int i = 0; i < 16; ++i) acc[m][nf][i] = 0.f;

    bf16x8 zed;
    #pragma unroll
    for (int e = 0; e < 8; ++e) zed[e] = (__bf16)0.f;

    int c0 = nbr[(size_t)sc0 * KK];
    int c1 = nbr[(size_t)sc1 * KK];
    stage(0, 0);
    __syncthreads();

    const int swq = (l31 & 7) << 4;

    #pragma unroll 1
    for (int k = 0; k < KK; ++k) {
        int n0 = 0, n1 = 0;
        if (k + 1 < KK) {
            n0 = nbr[(size_t)sc0 * KK + k + 1];
            n1 = nbr[(size_t)sc1 * KK + k + 1];
            stage((k + 1) & 1, k + 1);
        }

        const bool v0 = (unsigned)c0 < (unsigned)n;
        const bool v1 = (unsigned)c1 < (unsigned)n;
        const size_t rr0 = (size_t)(v0 ? c0 : 0) * CD;
        const size_t rr1 = (size_t)(v1 ? c1 : 0) * CD;

        bf16x8 a0[8], a1[8];
        #pragma unroll
        for (int cs = 0; cs < 8; ++cs) {
            const int coff = cs * 16 + kh * 8;
            f32x4 lo0 = *(const f32x4*)(feats + rr0 + coff);
            f32x4 hi0 = *(const f32x4*)(feats + rr0 + coff + 4);
            f32x4 lo1 = *(const f32x4*)(feats + rr1 + coff);
            f32x4 hi1 = *(const f32x4*)(feats + rr1 + coff + 4);
            #pragma unroll
            for (int e = 0; e < 4; ++e) {
                a0[cs][e] = (__bf16)lo0[e]; a0[cs][e + 4] = (__bf16)hi0[e];
                a1[cs][e] = (__bf16)lo1[e]; a1[cs][e + 4] = (__bf16)hi1[e];
            }
            a0[cs] = v0 ? a0[cs] : zed;
            a1[cs] = v1 ? a1[cs] : zed;
        }

        const char* wb = &wbuf[k & 1][0];
        #pragma unroll
        for (int cs = 0; cs < 8; ++cs) {
            #pragma unroll
            for (int nf = 0; nf < 4; ++nf) {
                const int x = ((nf * 32 + l31) << 8) + (cs << 5) + (kh << 4);
                bf16x8 b = *(const bf16x8*)(wb + (x ^ swq));
                acc[0][nf] = __builtin_amdgcn_mfma_f32_32x32x16_bf16(a0[cs], b, acc[0][nf], 0, 0, 0);
                acc[1][nf] = __builtin_amdgcn_mfma_f32_32x32x16_bf16(a1[cs], b, acc[1][nf], 0, 0, 0);
            }
        }

        __syncthreads();
        c0 = n0; c1 = n1;
    }

    #pragma unroll
    for (int m = 0; m < 2; ++m) {
        #pragma unroll
        for (int rg = 0; rg < 16; ++rg) {
            const int row  = (rg & 3) + 8 * (rg >> 2) + 4 * kh;
            const int srow = base + m * 32 + row;
            if (srow < n) {
                #pragma unroll
                for (int nf = 0; nf < 4; ++nf) {
                    float v = acc[m][nf][rg];
                    v = v > 0.f ? v : 0.f;
                    hout[(size_t)srow * CD + nf * 32 + l31] =
                        __builtin_bit_cast(unsigned short, (__bf16)v);
                }
            }
        }
    }
}

// ---------------------------------------------------------------------------
// conv2 — R3 structure (M=32 x 128 out, 512-thr, dbuf LDS, 1 barrier/tap,
// 4 waves/SIMD: the best measured 152us) + IN-PLACE A pipelining:
// inside tap k's MFMA phase, as soon as acur[cs] has fed its 4 MFMAs it is
// overwritten with the tap-(k+1) gather (validity mask deferred to use
// time). Reloads get ~220cy of MFMA cover + barrier skew before the
// barrier's drain, and the use-wait next iteration is nearly free.
// Zero extra registers vs R3 (no anxt buffer) -> (512,4) holds without
// spills (R7 lesson: VGPR budget 512/minwaves must exceed ~130).
// nbr indices roll two taps ahead. Cached gathers (R6: NT was null);
// NT only for the full-line residual/out streams.
// ---------------------------------------------------------------------------
__global__ __launch_bounds__(512, 4) void conv2_kernel(
    const float* __restrict__ feats,        // residual
    const unsigned short* __restrict__ asrc,// bf16 hid
    const unsigned short* __restrict__ WT,  // bf16 W_T[k][o][c] linear
    const int* __restrict__ nbr,
    float* __restrict__ fout,
    const int n)
{
    __shared__ __align__(16) char wbuf[2][32768];

    const int tid  = threadIdx.x;
    const int lane = tid & 63;
    const int l31  = lane & 31;
    const int kh   = lane >> 5;
    const int wave = tid >> 6;              // 0..7
    const int base = blockIdx.x * 256 + wave * 32;
    const int s0 = base + l31;
    const int sc0 = (s0 < n) ? s0 : (n - 1);

    auto stage = [&](int b, int k) {
        const char* tap = (const char*)(WT + (size_t)k * CD * CD);
        char* lb = &wbuf[b][0];
        #pragma unroll
        for (int i = 0; i < 4; ++i) {
            const int chunk = (i * 8 + wave) * 1024;
            const int d = chunk + lane * 16;
            const int s = d ^ (((d >> 8) & 7) << 4);
            __builtin_amdgcn_global_load_lds((gas_ptr)(tap + s),
                                             (las_ptr)(lb + chunk), 16, 0, 0);
        }
    };

    f32x16 acc[4];
    #pragma unroll
    for (int nf = 0; nf < 4; ++nf)
        #pragma unroll
        for (int i = 0; i < 16; ++i) acc[nf][i] = 0.f;

    bf16x8 zed;
    #pragma unroll
    for (int e = 0; e < 8; ++e) zed[e] = (__bf16)0.f;

    // prologue: idx for taps 0,1; raw gather of tap 0; stage tap 0
    int ccur = nbr[(size_t)sc0 * KK];
    int cnxt = nbr[(size_t)sc0 * KK + 1];
    bool vcur = (unsigned)ccur < (unsigned)n;
    {
        const size_t rr = (size_t)(vcur ? ccur : 0) * CD;
        // raw (unmasked) gather; mask applied at use
        bf16x8* dummy;
        (void)dummy;
    }
    bf16x8 acur[8];
    {
        const size_t rr = (size_t)(vcur ? ccur : 0) * CD;
        #pragma unroll
        for (int cs = 0; cs < 8; ++cs)
            acur[cs] = *(const bf16x8*)(asrc + rr + cs * 16 + kh * 8);
    }
    stage(0, 0);
    __syncthreads();

    const int swq = (l31 & 7) << 4;

    #pragma unroll 1
    for (int k = 0; k < KK; ++k) {
        int cnn = 0;
        if (k + 2 < KK) cnn = nbr[(size_t)sc0 * KK + k + 2];

        bool vnxt = false;
        size_t rrn = 0;
        if (k + 1 < KK) {
            stage((k + 1) & 1, k + 1);
            vnxt = (unsigned)cnxt < (unsigned)n;
            rrn  = (size_t)(vnxt ? cnxt : 0) * CD;
        }

        const char* wb = &wbuf[k & 1][0];
        #pragma unroll
        for (int cs = 0; cs < 8; ++cs) {
            const bf16x8 am = vcur ? acur[cs] : zed;   // deferred mask
            #pragma unroll
            for (int nf = 0; nf < 4; ++nf) {
                const int x = ((nf * 32 + l31) << 8) + (cs << 5) + (kh << 4);
                bf16x8 b = *(const bf16x8*)(wb + (x ^ swq));
                acc[nf] = __builtin_amdgcn_mfma_f32_32x32x16_bf16(am, b, acc[nf], 0, 0, 0);
            }
            if (k + 1 < KK)   // in-place reload for tap k+1 (raw)
                acur[cs] = *(const bf16x8*)(asrc + rrn + cs * 16 + kh * 8);
        }

        __syncthreads();   // drains stage(k+1); reloads mostly complete too
        vcur = vnxt; cnxt = cnn;
    }

    // Epilogue: col=lane&31, row=(rg&3)+8*(rg>>2)+4*kh; NT full-line streams
    #pragma unroll
    for (int rg = 0; rg < 16; ++rg) {
        const int row  = (rg & 3) + 8 * (rg >> 2) + 4 * kh;
        const int srow = base + row;
        if (srow < n) {
            #pragma unroll
            for (int nf = 0; nf < 4; ++nf) {
                float v = acc[nf][rg];
                const size_t oi = (size_t)srow * CD + nf * 32 + l31;
                v += __builtin_nontemporal_load(feats + oi);
                v = v > 0.f ? v : 0.f;
                __builtin_nontemporal_store(v, fout + oi);
            }
        }
    }
}

extern "C" void kernel_launch(void* const* d_in, const int* in_sizes, int n_in,
                              void* d_out, int out_size, void* d_ws, size_t ws_size,
                              hipStream_t stream) {
    const float* feats = (const float*)d_in[0];
    const int*   nbr   = (const int*)d_in[1];
    const float* W1    = (const float*)d_in[2];
    const float* W2    = (const float*)d_in[3];
    float* out = (float*)d_out;

    const int n = in_sizes[0] / CD;   // active sites (200000)

    unsigned short* hid = (unsigned short*)d_ws;
    unsigned short* W1T = hid + (size_t)n * CD;
    unsigned short* W2T = W1T + KK * CD * CD;

    transpose_w<<<2 * KK, 256, 0, stream>>>(W1, W2, W1T, W2T);

    const int grid = (n + 255) / 256;   // 256 sites per block (both convs)
    conv1_kernel<<<grid, 256, 0, stream>>>(feats, W1T, nbr, hid, n);
    conv2_kernel<<<grid, 512, 0, stream>>>(feats, hid, W2T, nbr, out, n);
}

// Round 9
// 219.229 us; speedup vs baseline: 13.0645x; 1.6854x over previous
//
#include <hip/hip_runtime.h>

#define CD 128   // channels
#define KK 9     // 3x3 kernel taps

typedef __bf16 bf16x8 __attribute__((ext_vector_type(8)));
typedef float  f32x4  __attribute__((ext_vector_type(4)));
typedef float  f32x16 __attribute__((ext_vector_type(16)));

typedef __attribute__((address_space(1))) const void* gas_ptr;
typedef __attribute__((address_space(3))) void*       las_ptr;

// ---------------------------------------------------------------------------
// Cast feats f32 -> bf16, linear streaming. ~153MB traffic ≈ 25-30us.
// ---------------------------------------------------------------------------
__global__ __launch_bounds__(256) void cast_feats(const float* __restrict__ src,
                                                  unsigned short* __restrict__ dst,
                                                  const long total8) {  // n*CD/8
    const long stride = (long)gridDim.x * 256;
    for (long i = (long)blockIdx.x * 256 + threadIdx.x; i < total8; i += stride) {
        f32x4 lo = *(const f32x4*)(src + i * 8);
        f32x4 hi = *(const f32x4*)(src + i * 8 + 4);
        bf16x8 v;
        #pragma unroll
        for (int e = 0; e < 4; ++e) {
            v[e]     = (__bf16)lo[e];
            v[e + 4] = (__bf16)hi[e];
        }
        *(bf16x8*)(dst + i * 8) = v;
    }
}

// ---------------------------------------------------------------------------
// Transpose + cast W[k][c][o] (f32) -> W_T[k][o][c] (bf16 bits), linear layout.
// ---------------------------------------------------------------------------
__global__ __launch_bounds__(256) void transpose_w(const float* __restrict__ W1,
                                                   const float* __restrict__ W2,
                                                   unsigned short* __restrict__ W1T,
                                                   unsigned short* __restrict__ W2T) {
    __shared__ unsigned short tile[128 * 129];
    const int b = blockIdx.x;            // 0..17
    const int k = (b < KK) ? b : b - KK;
    const float* src = ((b < KK) ? W1 : W2) + k * (CD * CD);
    unsigned short* dst = ((b < KK) ? W1T : W2T) + k * (CD * CD);
    #pragma unroll 4
    for (int p = 0; p < 64; ++p) {
        int idx = p * 256 + threadIdx.x;     // coalesced read W[k][c][o]
        int c = idx >> 7, o = idx & 127;
        __bf16 h = (__bf16)src[idx];
        tile[o * 129 + c] = __builtin_bit_cast(unsigned short, h);
    }
    __syncthreads();
    #pragma unroll 4
    for (int p = 0; p < 64; ++p) {
        int idx = p * 256 + threadIdx.x;     // coalesced write W_T[k][o][c]
        int o = idx >> 7, c = idx & 127;
        dst[idx] = tile[o * 129 + c];
    }
}

// ---------------------------------------------------------------------------
// Shared conv body — the R2 structure, best measured (conv2@67us):
// wave = 64 sites (2 M-frags) x 128 out (4 N-frags), 256-thr block,
// 2 waves/SIMD. Weights double-buffered in LDS (2x32KB) via global_load_lds
// w=16, XOR swizzle on the GLOBAL source (linear LDS dest), same XOR on
// ds_read. nbr prefetched one tap ahead; A-gathers (bf16, CACHED) batched
// up front. Cached epilogue stores (NT hurt or was null in R3/R6).
// ---------------------------------------------------------------------------
template <bool FIRST>
__device__ __forceinline__ void conv_body(
    const unsigned short* __restrict__ asrc,   // bf16 A source [n][128]
    const float* __restrict__ resid,           // f32 residual (!FIRST)
    const unsigned short* __restrict__ WT,     // bf16 W_T[k][o][c] linear
    const int* __restrict__ nbr,               // [n][9]
    unsigned short* __restrict__ hout,         // bf16 out (FIRST)
    float* __restrict__ fout,                  // f32 out (!FIRST)
    const int n, char (*wbuf)[32768])
{
    const int tid  = threadIdx.x;
    const int lane = tid & 63;
    const int l31  = lane & 31;
    const int kh   = lane >> 5;
    const int wave = tid >> 6;
    const int base = blockIdx.x * 256 + wave * 64;
    const int s0 = base + l31;
    const int s1 = base + 32 + l31;
    const int sc0 = (s0 < n) ? s0 : (n - 1);
    const int sc1 = (s1 < n) ? s1 : (n - 1);

    auto stage = [&](int b, int k) {
        const char* tap = (const char*)(WT + (size_t)k * CD * CD);
        char* lb = &wbuf[b][0];
        #pragma unroll
        for (int i = 0; i < 8; ++i) {
            const int chunk = (i * 4 + wave) * 1024;
            const int d = chunk + lane * 16;
            const int s = d ^ (((d >> 8) & 7) << 4);
            __builtin_amdgcn_global_load_lds((gas_ptr)(tap + s),
                                             (las_ptr)(lb + chunk), 16, 0, 0);
        }
    };

    f32x16 acc[2][4];
    #pragma unroll
    for (int m = 0; m < 2; ++m)
        #pragma unroll
        for (int nf = 0; nf < 4; ++nf)
            #pragma unroll
            for (int i = 0; i < 16; ++i) acc[m][nf][i] = 0.f;

    bf16x8 zed;
    #pragma unroll
    for (int e = 0; e < 8; ++e) zed[e] = (__bf16)0.f;

    int c0 = nbr[(size_t)sc0 * KK];
    int c1 = nbr[(size_t)sc1 * KK];
    stage(0, 0);
    __syncthreads();

    const int swq = (l31 & 7) << 4;

    #pragma unroll 1
    for (int k = 0; k < KK; ++k) {
        int n0 = 0, n1 = 0;
        if (k + 1 < KK) {
            n0 = nbr[(size_t)sc0 * KK + k + 1];
            n1 = nbr[(size_t)sc1 * KK + k + 1];
            stage((k + 1) & 1, k + 1);
        }

        const bool v0 = (unsigned)c0 < (unsigned)n;
        const bool v1 = (unsigned)c1 < (unsigned)n;
        const size_t rr0 = (size_t)(v0 ? c0 : 0) * CD;
        const size_t rr1 = (size_t)(v1 ? c1 : 0) * CD;

        bf16x8 a0[8], a1[8];
        #pragma unroll
        for (int cs = 0; cs < 8; ++cs) {
            const int coff = cs * 16 + kh * 8;
            a0[cs] = *(const bf16x8*)(asrc + rr0 + coff);
            a1[cs] = *(const bf16x8*)(asrc + rr1 + coff);
            a0[cs] = v0 ? a0[cs] : zed;
            a1[cs] = v1 ? a1[cs] : zed;
        }

        const char* wb = &wbuf[k & 1][0];
        #pragma unroll
        for (int cs = 0; cs < 8; ++cs) {
            #pragma unroll
            for (int nf = 0; nf < 4; ++nf) {
                const int x = ((nf * 32 + l31) << 8) + (cs << 5) + (kh << 4);
                bf16x8 b = *(const bf16x8*)(wb + (x ^ swq));
                acc[0][nf] = __builtin_amdgcn_mfma_f32_32x32x16_bf16(a0[cs], b, acc[0][nf], 0, 0, 0);
                acc[1][nf] = __builtin_amdgcn_mfma_f32_32x32x16_bf16(a1[cs], b, acc[1][nf], 0, 0, 0);
            }
        }

        __syncthreads();
        c0 = n0; c1 = n1;
    }

    // Epilogue (cached): C/D map col=lane&31, row=(rg&3)+8*(rg>>2)+4*kh
    #pragma unroll
    for (int m = 0; m < 2; ++m) {
        #pragma unroll
        for (int rg = 0; rg < 16; ++rg) {
            const int row  = (rg & 3) + 8 * (rg >> 2) + 4 * kh;
            const int srow = base + m * 32 + row;
            if (srow < n) {
                #pragma unroll
                for (int nf = 0; nf < 4; ++nf) {
                    float v = acc[m][nf][rg];
                    const size_t oi = (size_t)srow * CD + nf * 32 + l31;
                    if (FIRST) {
                        v = v > 0.f ? v : 0.f;
                        hout[oi] = __builtin_bit_cast(unsigned short, (__bf16)v);
                    } else {
                        v += resid[oi];
                        v = v > 0.f ? v : 0.f;
                        fout[oi] = v;
                    }
                }
            }
        }
    }
}

__global__ __launch_bounds__(256, 2) void conv1_kernel(
    const unsigned short* __restrict__ fb16,
    const unsigned short* __restrict__ WT,
    const int* __restrict__ nbr,
    unsigned short* __restrict__ hout,
    const int n)
{
    __shared__ __align__(16) char wbuf[2][32768];
    conv_body<true>(fb16, nullptr, WT, nbr, hout, nullptr, n, wbuf);
}

__global__ __launch_bounds__(256, 2) void conv2_kernel(
    const unsigned short* __restrict__ hid,
    const float* __restrict__ feats,
    const unsigned short* __restrict__ WT,
    const int* __restrict__ nbr,
    float* __restrict__ fout,
    const int n)
{
    __shared__ __align__(16) char wbuf[2][32768];
    conv_body<false>(hid, feats, WT, nbr, nullptr, fout, n, wbuf);
}

extern "C" void kernel_launch(void* const* d_in, const int* in_sizes, int n_in,
                              void* d_out, int out_size, void* d_ws, size_t ws_size,
                              hipStream_t stream) {
    const float* feats = (const float*)d_in[0];
    const int*   nbr   = (const int*)d_in[1];
    const float* W1    = (const float*)d_in[2];
    const float* W2    = (const float*)d_in[3];
    float* out = (float*)d_out;

    const int n = in_sizes[0] / CD;   // active sites (200000)

    // workspace layout: hid [n][128] bf16, W1T, W2T, fbf16 [n][128] bf16
    unsigned short* hid  = (unsigned short*)d_ws;
    unsigned short* W1T  = hid + (size_t)n * CD;
    unsigned short* W2T  = W1T + KK * CD * CD;
    unsigned short* fb16 = W2T + KK * CD * CD;
    const size_t need = ((size_t)n * CD * 2 + (size_t)2 * KK * CD * CD) * 2;
    if (ws_size < need) {
        // fall back: put fbf16 in d_out's first half; conv1 consumes it
        // before conv2 overwrites every element of d_out. Deterministic.
        fb16 = (unsigned short*)d_out;
    }

    const long total8 = (long)n * CD / 8;
    cast_feats<<<2048, 256, 0, stream>>>(feats, fb16, total8);
    transpose_w<<<2 * KK, 256, 0, stream>>>(W1, W2, W1T, W2T);

    const int grid = (n + 255) / 256;   // 256 sites per 4-wave block
    conv1_kernel<<<grid, 256, 0, stream>>>(fb16, W1T, nbr, hid, n);
    conv2_kernel<<<grid, 256, 0, stream>>>(hid, feats, W2T, nbr, out, n);
}